// Round 2
// baseline (382.029 us; speedup 1.0000x reference)
//
#include <hip/hip_runtime.h>

// BayesianLayer: out[b,o] = sum_i x[b,i]*(eps[b,i,o]*softplus(ro[i,o]) + mu[i,o])
//                          + eps_bias[b,o]*softplus(ro_bias[o]) + mu_bias[o]
// B=64, IN=1024, OUT=1024, fp32. Memory-bound on eps (256 MiB, read-once).
//
// R2 post-mortem: 4x occupancy (8->32 waves/CU) changed nothing => main was
// never latency-bound. R3 removes the common-mode suspect (nontemporal load
// on the eps stream), folds softplus into main (kills sig kernel + buffer),
// reverts to ICH=32 (8 MB part, L2/L3-resident, plain stores), and
// parallelizes reduce 4x via sub-lane split.
//
// Deterministic 2-kernel pipeline (NO atomics, NO output memset):
//   B: part[b,c,o] = sum_{i in chunk c} x*(eps*softplus(ro)+mu) -> ws
//   C: out[b,o]    = sum_c part + eps_bias*softplus(ro_bias) + mu_bias

#define BB   64
#define INN  1024
#define OUTT 1024
#define B_T  2               // batch rows per main block
#define ICH  32              // split-K chunks over IN
#define I_C  (INN / ICH)     // 32 i's per main block

typedef float f4 __attribute__((ext_vector_type(4)));

// Fast softplus: max(v,0) + log(1+exp(-|v|)). __logf arg is in (1,2] so the
// fast log2-based path is accurate there; error << fp32 split-K reorder noise.
__device__ __forceinline__ float softplus_f(float v) {
    return fmaxf(v, 0.0f) + __logf(1.0f + __expf(-fabsf(v)));
}

// ---- kernel B: split-K partials, softplus fused ----
// grid (ICH, BB/B_T) = (32, 32) = 1024 blocks, 4 blocks/CU, 16 waves/CU.
// Blocks sharing chunk c are 32 apart in linear id (32 % 8 XCDs == 0) ->
// same XCD -> ro/mu rows fetched once per L2 and reused 32x locally.
__global__ __launch_bounds__(256) void bayes_main(
    const float* __restrict__ x,        // [B, IN]
    const float* __restrict__ mu,       // [IN, OUT]
    const float* __restrict__ ro,       // [IN, OUT]
    const float* __restrict__ eps,      // [B, IN, OUT]
    float* __restrict__ part)           // [B, ICH, OUT]
{
    __shared__ float xs[B_T][I_C];

    const int t  = threadIdx.x;
    const int o  = t << 2;
    const int c  = blockIdx.x;          // chunk
    const int b0 = blockIdx.y * B_T;
    const int i0 = c * I_C;

    if (t < B_T * I_C) {                // 64 threads stage x
        const int b  = t / I_C;
        const int il = t % I_C;
        xs[b][il] = x[(b0 + b) * INN + i0 + il];
    }
    __syncthreads();

    f4 acc[B_T];
#pragma unroll
    for (int b = 0; b < B_T; ++b) acc[b] = (f4)0.0f;

#pragma unroll 4
    for (int il = 0; il < I_C; ++il) {
        const int i = i0 + il;
        const f4 r4 = *(const f4*)(ro + (size_t)i * OUTT + o);
        const f4 m4 = *(const f4*)(mu + (size_t)i * OUTT + o);
        f4 sg;
        sg.x = softplus_f(r4.x); sg.y = softplus_f(r4.y);
        sg.z = softplus_f(r4.z); sg.w = softplus_f(r4.w);
#pragma unroll
        for (int b = 0; b < B_T; ++b) {
            const float xb = xs[b][il];
            // PLAIN load (R3): nontemporal hint removed — common-mode suspect
            // for the ~1.8 TB/s eps ceiling across R0/R1.
            const f4 e = *(const f4*)(eps + ((size_t)(b0 + b) * INN + i) * OUTT + o);
            acc[b].x = fmaf(xb, fmaf(e.x, sg.x, m4.x), acc[b].x);
            acc[b].y = fmaf(xb, fmaf(e.y, sg.y, m4.y), acc[b].y);
            acc[b].z = fmaf(xb, fmaf(e.z, sg.z, m4.z), acc[b].z);
            acc[b].w = fmaf(xb, fmaf(e.w, sg.w, m4.w), acc[b].w);
        }
    }

#pragma unroll
    for (int b = 0; b < B_T; ++b) {
        // Plain store: keep part L2/L3-resident for the reduce pass.
        *(f4*)(part + ((size_t)(b0 + b) * ICH + c) * OUTT + o) = acc[b];
    }
}

// ---- kernel C: reduce 32 partials + bias ----
// 256 blocks x 256 threads; 4 threads per f4 output (8 chunks each),
// combined with __shfl_xor within 4-lane groups.
__global__ __launch_bounds__(256) void bayes_reduce(
    const float* __restrict__ part,     // [B, ICH, OUT]
    const float* __restrict__ mu_bias,  // [OUT]
    const float* __restrict__ ro_bias,  // [OUT]
    const float* __restrict__ eps_bias, // [B, OUT]
    float* __restrict__ out)            // [B, OUT]
{
    const int t   = threadIdx.x;
    const int g   = blockIdx.x * 64 + (t >> 2);   // f4 output index in [0,16384)
    const int sub = t & 3;
    const int b   = g >> 8;                       // 256 f4 per row
    const int o   = (g & 255) << 2;

    f4 s = (f4)0.0f;
    const int c0 = sub * (ICH / 4);
#pragma unroll
    for (int cc = 0; cc < ICH / 4; ++cc) {
        const f4 p = *(const f4*)(part + ((size_t)b * ICH + c0 + cc) * OUTT + o);
        s.x += p.x; s.y += p.y; s.z += p.z; s.w += p.w;
    }

    // combine the 4 sub-lanes (adjacent lanes of the same wave)
#pragma unroll
    for (int m = 1; m < 4; m <<= 1) {
        s.x += __shfl_xor(s.x, m, 4);
        s.y += __shfl_xor(s.y, m, 4);
        s.z += __shfl_xor(s.z, m, 4);
        s.w += __shfl_xor(s.w, m, 4);
    }

    if (sub == 0) {
        const f4 rb = *(const f4*)(ro_bias + o);
        const f4 mb = *(const f4*)(mu_bias + o);
        const f4 eb = *(const f4*)(eps_bias + (size_t)b * OUTT + o);
        s.x += fmaf(eb.x, softplus_f(rb.x), mb.x);
        s.y += fmaf(eb.y, softplus_f(rb.y), mb.y);
        s.z += fmaf(eb.z, softplus_f(rb.z), mb.z);
        s.w += fmaf(eb.w, softplus_f(rb.w), mb.w);
        *(f4*)(out + (size_t)g * 4) = s;
    }
}

// ---- fallback (ws too small): single deterministic kernel, no scratch ----
__global__ __launch_bounds__(256) void bayes_mono(
    const float* __restrict__ x, const float* __restrict__ mu,
    const float* __restrict__ ro, const float* __restrict__ mu_bias,
    const float* __restrict__ ro_bias, const float* __restrict__ eps,
    const float* __restrict__ eps_bias, float* __restrict__ out)
{
    const int t = threadIdx.x;
    const int o = t << 2;
    const int b = blockIdx.x;

    f4 acc = (f4)0.0f;
    for (int i = 0; i < INN; ++i) {
        const float xb = x[b * INN + i];
        const f4 r4 = *(const f4*)(ro + (size_t)i * OUTT + o);
        const f4 m4 = *(const f4*)(mu + (size_t)i * OUTT + o);
        const f4 e  = *(const f4*)(eps + ((size_t)b * INN + i) * OUTT + o);
        acc.x = fmaf(xb, fmaf(e.x, softplus_f(r4.x), m4.x), acc.x);
        acc.y = fmaf(xb, fmaf(e.y, softplus_f(r4.y), m4.y), acc.y);
        acc.z = fmaf(xb, fmaf(e.z, softplus_f(r4.z), m4.z), acc.z);
        acc.w = fmaf(xb, fmaf(e.w, softplus_f(r4.w), m4.w), acc.w);
    }
    const f4 rb = *(const f4*)(ro_bias + o);
    const f4 mb = *(const f4*)(mu_bias + o);
    const f4 eb = *(const f4*)(eps_bias + (size_t)b * OUTT + o);
    acc.x += fmaf(eb.x, softplus_f(rb.x), mb.x);
    acc.y += fmaf(eb.y, softplus_f(rb.y), mb.y);
    acc.z += fmaf(eb.z, softplus_f(rb.z), mb.z);
    acc.w += fmaf(eb.w, softplus_f(rb.w), mb.w);
    *(f4*)(out + (size_t)b * OUTT + o) = acc;
}

extern "C" void kernel_launch(void* const* d_in, const int* in_sizes, int n_in,
                              void* d_out, int out_size, void* d_ws, size_t ws_size,
                              hipStream_t stream) {
    const float* x        = (const float*)d_in[0];
    const float* mu       = (const float*)d_in[1];
    const float* ro       = (const float*)d_in[2];
    const float* mu_bias  = (const float*)d_in[3];
    const float* ro_bias  = (const float*)d_in[4];
    const float* eps      = (const float*)d_in[5];
    const float* eps_bias = (const float*)d_in[6];
    float* out = (float*)d_out;

    const size_t part_elems = (size_t)BB * ICH * OUTT;   // 2M floats, 8 MB
    const size_t need = part_elems * sizeof(float);

    if (ws_size >= need) {
        float* part = (float*)d_ws;

        dim3 grid(ICH, BB / B_T);   // 32 x 32 = 1024 blocks, 4 blocks/CU
        bayes_main<<<grid, 256, 0, stream>>>(x, mu, ro, eps, part);
        bayes_reduce<<<256, 256, 0, stream>>>(
            part, mu_bias, ro_bias, eps_bias, out);
    } else {
        bayes_mono<<<BB, 256, 0, stream>>>(x, mu, ro, mu_bias, ro_bias,
                                           eps, eps_bias, out);
    }
}